// Round 1
// baseline (335.872 us; speedup 1.0000x reference)
//
#include <hip/hip_runtime.h>
#include <math.h>

#define BATCH 256
#define PRE   64     // k
#define NEXT  32     // K
#define DIN   128    // d
#define DOUT  64     // D

// ---------------- GEMM: p[b,k,K,D] = sum_d x[b,k,d] * W[k,K,d,D] ----------------
// block: 256 threads, output tile 128 b-rows x 64 D-cols, d staged in chunks of 64.
// xT in LDS transposed [d][row] (stride 132: 16B-aligned reads, spreads banks),
// W slab [d][D] staged contiguously. Per-thread tile 8x4.
#define DCH 64
#define XT_STRIDE 132

__global__ __launch_bounds__(256) void gemm_kernel(const float* __restrict__ x,
                                                   const float* __restrict__ W,
                                                   float* __restrict__ p,
                                                   int b0)
{
    __shared__ float xT[DCH * XT_STRIDE];
    __shared__ float Wl[DCH * DOUT];
    const int K     = blockIdx.x;
    const int btile = blockIdx.y;
    const int k     = blockIdx.z;
    const int t  = threadIdx.x;
    const int tx = t & 15;        // D / 4
    const int ty = t >> 4;        // row / 8

    float acc[8][4];
#pragma unroll
    for (int r = 0; r < 8; ++r)
#pragma unroll
        for (int c = 0; c < 4; ++c) acc[r][c] = 0.f;

    for (int dc = 0; dc < DIN; dc += DCH) {
        __syncthreads();
        // stage x: 128 rows x 64 d = 2048 float4, transpose into xT[d][row]
        {
            const float4* xg4 = (const float4*)x;
#pragma unroll
            for (int i = 0; i < 8; ++i) {
                int f  = t + 256 * i;          // 0..2047
                int r  = f >> 4;               // 16 float4 per row
                int d4 = f & 15;
                int gi4 = (((b0 + btile * 128 + r) * PRE + k) * DIN + dc) / 4 + d4;
                float4 v = xg4[gi4];
                int dd = d4 * 4;
                xT[(dd + 0) * XT_STRIDE + r] = v.x;
                xT[(dd + 1) * XT_STRIDE + r] = v.y;
                xT[(dd + 2) * XT_STRIDE + r] = v.z;
                xT[(dd + 3) * XT_STRIDE + r] = v.w;
            }
        }
        // stage W slab: 64 d x 64 D = 1024 float4, contiguous copy
        {
            const float4* Wg4 = (const float4*)W;
            float4* Wl4 = (float4*)Wl;
            int slab4 = (((k * NEXT + K) * DIN + dc) * DOUT) / 4;
#pragma unroll
            for (int i = 0; i < 4; ++i) {
                int f = t + 256 * i;
                Wl4[f] = Wg4[slab4 + f];
            }
        }
        __syncthreads();
#pragma unroll 8
        for (int d = 0; d < DCH; ++d) {
            float4 xa = *(const float4*)&xT[d * XT_STRIDE + ty * 8];
            float4 xb = *(const float4*)&xT[d * XT_STRIDE + ty * 8 + 4];
            float4 wv = *(const float4*)&Wl[d * DOUT + tx * 4];
            float xr[8] = {xa.x, xa.y, xa.z, xa.w, xb.x, xb.y, xb.z, xb.w};
            float wc[4] = {wv.x, wv.y, wv.z, wv.w};
#pragma unroll
            for (int r = 0; r < 8; ++r)
#pragma unroll
                for (int c = 0; c < 4; ++c)
                    acc[r][c] += xr[r] * wc[c];
        }
    }
    // store p[bl,k,K,D], bl local to this ws chunk
#pragma unroll
    for (int r = 0; r < 8; ++r) {
        int bl = btile * 128 + ty * 8 + r;
        float4 v = {acc[r][0], acc[r][1], acc[r][2], acc[r][3]};
        ((float4*)p)[(size_t)((bl * PRE + k) * NEXT + K) * 16 + tx] = v;
    }
}

// ---------------- Routing: 3 fused passes over p, one block per b ----------------
// 512 threads = 8 waves; wave w handles k = i*8 + w.
// lane -> (K = lane>>1, half = lane&1) covering 32 D-elements each.
// Softmax over K entirely via in-wave shfl_xor (logits pair-duplicated).
// q accumulator in LDS with stride-33 padding: slice s = lane, bank = (lane+j)%32.
__global__ __launch_bounds__(512) void route_kernel(const float* __restrict__ p,
                                                    float* __restrict__ out,
                                                    int b0)
{
    __shared__ float qsh[64 * 33];   // [slice = K*2+half][33]
    const int b    = blockIdx.x;     // local b within chunk
    const int t    = threadIdx.x;
    const int wave = t >> 6;
    const int lane = t & 63;
    const int K    = lane >> 1;
    const int half = lane & 1;
    const float* pb = p + (size_t)b * (PRE * NEXT * DOUT);

    float qcur[32], qacc[32], blog[8];
#pragma unroll
    for (int i = 0; i < 8; ++i) blog[i] = 0.f;

    for (int pass = 0; pass < 3; ++pass) {
        for (int i = t; i < 64 * 33; i += 512) qsh[i] = 0.f;
#pragma unroll
        for (int j = 0; j < 32; ++j) qacc[j] = 0.f;
        __syncthreads();

        float4 pv[2][8];
        {
            const float4* pk = (const float4*)(pb + (size_t)wave * (NEXT * DOUT) + K * 64 + half * 32);
#pragma unroll
            for (int j = 0; j < 8; ++j) pv[0][j] = pk[j];
        }
#pragma unroll
        for (int i = 0; i < 8; ++i) {
            const int buf = i & 1;
            if (i < 7) {
                const float4* pk = (const float4*)(pb + (size_t)((i + 1) * 8 + wave) * (NEXT * DOUT) + K * 64 + half * 32);
#pragma unroll
                for (int j = 0; j < 8; ++j) pv[buf ^ 1][j] = pk[j];
            }
            float c;
            if (pass == 0) {
                c = 1.0f / 32.0f;          // softmax of zeros
            } else {
                float delta = 0.f;
#pragma unroll
                for (int j = 0; j < 8; ++j) {
                    delta += pv[buf][j].x * qcur[j * 4 + 0];
                    delta += pv[buf][j].y * qcur[j * 4 + 1];
                    delta += pv[buf][j].z * qcur[j * 4 + 2];
                    delta += pv[buf][j].w * qcur[j * 4 + 3];
                }
                delta += __shfl_xor(delta, 1);       // full dot over D=64, pair-duplicated
                blog[i] += delta;
                float m = blog[i];
                m = fmaxf(m, __shfl_xor(m, 2));
                m = fmaxf(m, __shfl_xor(m, 4));
                m = fmaxf(m, __shfl_xor(m, 8));
                m = fmaxf(m, __shfl_xor(m, 16));
                m = fmaxf(m, __shfl_xor(m, 32));
                float e = __expf(blog[i] - m);
                float s = e;
                s += __shfl_xor(s, 2);
                s += __shfl_xor(s, 4);
                s += __shfl_xor(s, 8);
                s += __shfl_xor(s, 16);
                s += __shfl_xor(s, 32);              // sum over the 32 distinct K
                c = e / s;
            }
#pragma unroll
            for (int j = 0; j < 8; ++j) {
                qacc[j * 4 + 0] += c * pv[buf][j].x;
                qacc[j * 4 + 1] += c * pv[buf][j].y;
                qacc[j * 4 + 2] += c * pv[buf][j].z;
                qacc[j * 4 + 3] += c * pv[buf][j].w;
            }
        }
        // cross-wave reduce into padded LDS (bank-conflict-free: bank=(lane+j)%32)
#pragma unroll
        for (int j = 0; j < 32; ++j) atomicAdd(&qsh[lane * 33 + j], qacc[j]);
        __syncthreads();

        // squash per K: 16 threads per K, 4 elems each
        {
            const int Kq = t >> 4, e = t & 15;
            const int D0 = e * 4;
            const int h  = D0 >> 5, j0 = D0 & 31;
            const int sbase = (Kq * 2 + h) * 33 + j0;
            float v0 = qsh[sbase + 0];
            float v1 = qsh[sbase + 1];
            float v2 = qsh[sbase + 2];
            float v3 = qsh[sbase + 3];
            float s2 = v0 * v0 + v1 * v1 + v2 * v2 + v3 * v3;
            s2 += __shfl_xor(s2, 1);
            s2 += __shfl_xor(s2, 2);
            s2 += __shfl_xor(s2, 4);
            s2 += __shfl_xor(s2, 8);
            float f = s2 / ((1.f + s2) * sqrtf(s2 + 1e-8f));
            v0 *= f; v1 *= f; v2 *= f; v3 *= f;
            if (pass < 2) {
                qsh[sbase + 0] = v0;
                qsh[sbase + 1] = v1;
                qsh[sbase + 2] = v2;
                qsh[sbase + 3] = v3;
            } else {
                float4 v = {v0, v1, v2, v3};
                ((float4*)out)[(size_t)(b0 + b) * 512 + Kq * 16 + e] = v;
            }
        }
        if (pass < 2) {
            __syncthreads();
#pragma unroll
            for (int j = 0; j < 32; ++j) qcur[j] = qsh[lane * 33 + j];
            __syncthreads();   // protect qsh before next-pass zeroing
        }
    }
}

extern "C" void kernel_launch(void* const* d_in, const int* in_sizes, int n_in,
                              void* d_out, int out_size, void* d_ws, size_t ws_size,
                              hipStream_t stream) {
    const float* x = (const float*)d_in[0];
    const float* W = (const float*)d_in[1];
    float* out = (float*)d_out;
    float* p   = (float*)d_ws;

    const size_t per_b = (size_t)PRE * NEXT * DOUT * sizeof(float);  // 512 KB
    int chunk = (ws_size >= per_b * BATCH) ? BATCH : 128;            // 128 MB or 64 MB ws

    for (int b0 = 0; b0 < BATCH; b0 += chunk) {
        dim3 g1(NEXT, chunk / 128, PRE);
        gemm_kernel<<<g1, 256, 0, stream>>>(x, W, p, b0);
        route_kernel<<<chunk, 512, 0, stream>>>(p, out, b0);
    }
}